// Round 4
// baseline (417.681 us; speedup 1.0000x reference)
//
#include <hip/hip_runtime.h>
#include <hip/hip_fp16.h>

// ---------------------------------------------------------------------------
// DeterministicLSTMSensorBasedForwardDynamics on MI355X (gfx950) — round 12
//
// r11 post-mortem (clean null): ring 8->13 + fused-rcp = 270 us vs r8 261.
// Deeper ring bought nothing -> depth-8 cover was already sufficient; +8.3%
// stream bytes cost +3% -> marginal stream cost ~0.36x port time. Corrected
// pipe model: one 16x16x32 f16 MFMA occupies its SIMD matrix pipe ~16 cyc
// (peak 1017 FLOP/cyc/SIMD), so per step per SIMD: 2 waves x 88 x 16 = 2816
// cyc = 23% of the 12.4K-cyc step == measured MfmaUtil. Pipes busy <=40%,
// i.e. >50% of the time BOTH waves of a SIMD stall together: with 2
// waves/SIMD (occupancy 22.6%) there is nothing to cover L2/LDS latency.
//
// Round 12 = 16-WAVE RESTRUCTURE (4 waves/SIMD), work per wave halved:
//   * NTHR 512 -> 1024, MTILE=16, NWG=256 (still exactly 1 WG/CU).
//   * wave w owns 16 output cols: tile nt = g*16 + w per gate g -> 44
//     MFMAs/wave, acc 16 regs, 4 cell-update chains/wave, bias[4].
//   * residency/wave: rw kt0..2 (12 blocks, 48 AGPR), Wc kt3..4 (8 blocks,
//     16 waves x 8 = 128 KB LDS, same as before), stream kt5..10 (24 blocks)
//     via 6-slot cross-step ring (24 % 6 == 0).
//   * per-CU stream unchanged at 384 KB/step (capacity conserved); the win
//     is 4-way wave interleave per SIMD covering vmcnt/lgkm stalls.
//   * register budget 128/wave (est ~124) enforced by __launch_bounds__(1024,4).
// Prediction: dur ~185-205 us, Occupancy ~45%, MfmaUtil ~35%, VALUBusy ~40%,
// VGPR ~64-80, bank conflicts ~2x (~10M), FETCH unchanged. Tripwire: WRITE
// >5 MB = spill at the 128-reg wall -> confounded. Clean null (>=250 us) ->
// wave-starvation theory wrong -> L2-delivery structural limit -> ROOFLINE.
// ---------------------------------------------------------------------------

typedef _Float16 h8 __attribute__((ext_vector_type(8)));
typedef _Float16 hv4 __attribute__((ext_vector_type(4)));
typedef float f4 __attribute__((ext_vector_type(4)));

#define NB    4096
#define TSEQ  50
#define DOBS  64
#define DACT  16
#define HD    256
#define DOUT  64
#define NL    5

#define NKT   11        // K-tiles of 32 covering 352 = 80 (x) + 256 (h) + 16 pad
#define AROW  360       // LDS A-row stride in halves
#define MTILE 16
#define NWG   (NB / MTILE)   // 256
#define NTHR  1024           // 16 waves

// ws layout in halves (written by repack_kernel)
#define WS_MLP   (704 * 512)
#define WS_WOUT  (WS_MLP + 640 * 512)

// LDS layout (halves): As0 | As1 | Wcache(16 waves x WCB blocks)
#define LDS_AS     (MTILE * AROW)      // 5760 per panel
#define LDS_WCOFF  (2 * LDS_AS)        // 11520
#define WCB        8                   // LDS-resident blocks per wave (kt3..4, g0..3)
#define LDS_HALVES (LDS_WCOFF + 16 * WCB * 512)  // 77056
#define LDS_BYTES  (LDS_HALVES * 2)              // 154112  (<= 160 KiB)
static_assert(LDS_BYTES <= 160 * 1024, "LDS overflow");

// Streaming per wave: kt5..10 x g0..3, position c = (kt-5)*4 + g, c in [0,24).
// Consumption is monotone in c; slot c%6 refilled with position (c+6)%24 at
// consumption of c. 24 % 6 == 0 -> the ring persists ACROSS steps (the last
// 6 refills of a step fetch the next step's positions 0..5).
#define SB_P     6
#define NSTREAM  24

// Barrier that does NOT drain vmcnt: cross-wave data dependencies at the
// t-loop barrier are ds_write-only (h and x panels), covered by lgkmcnt(0).
// In-flight global loads (stream ring, x prefetch) target private VGPRs and
// are synchronized by their own vmcnt-before-use waits -> legal to keep
// flying across s_barrier.
__device__ __forceinline__ void lds_barrier() {
  asm volatile("s_waitcnt lgkmcnt(0)\n\ts_barrier" ::: "memory");
}

// stream position c -> block offset (halves) rel. to wave base (w*NKT*512):
//   g = c&3, kt = 5 + (c>>2)  ->  ((g*16)*NKT + kt)*512   (w folded into base)
__device__ constexpr int soff(int c) {
  return (((c & 3) * 16) * NKT + 5 + (c >> 2)) * 512;
}

// --------------------------- weight repack ---------------------------------
__global__ void __launch_bounds__(256) repack_kernel(
    const float* __restrict__ Wi, const float* __restrict__ Wh,
    const float* __restrict__ mlpW, const float* __restrict__ Wout,
    _Float16* __restrict__ wsW)
{
  const int gt  = blockIdx.x * 256 + threadIdx.x;
  const int gb  = gt >> 6;
  const int l   = gt & 63;
  const int l15 = l & 15;
  const int kb  = (l >> 4) * 8;
  h8 v;
  if (gb < 704) {                       // LSTM: Wcat[k][n], k<80 -> Wi, k<336 -> Wh, else 0
    const int nt = gb / NKT, kt = gb - nt * NKT;
    const int n  = nt * 16 + l15;
#pragma unroll
    for (int j = 0; j < 8; ++j) {
      const int k = kt * 32 + kb + j;
      float s = 0.f;
      if (k < 80)       s = Wi[k * 1024 + n];
      else if (k < 336) s = Wh[(k - 80) * 1024 + n];
      v[j] = (_Float16)s;
    }
  } else if (gb < 1344) {               // MLP layer weights [5][256][256]
    const int b2 = gb - 704;
    const int L  = b2 >> 7, rr = b2 & 127;
    const int nt = rr >> 3, kt = rr & 7;
    const int n  = nt * 16 + l15;
#pragma unroll
    for (int j = 0; j < 8; ++j) {
      const int k = kt * 32 + kb + j;
      v[j] = (_Float16)mlpW[(size_t)L * 65536 + k * 256 + n];
    }
  } else {                              // Wout [256][64]
    const int b3 = gb - 1344;
    const int nt = b3 >> 3, kt = b3 & 7;
    const int n  = nt * 16 + l15;
#pragma unroll
    for (int j = 0; j < 8; ++j) {
      const int k = kt * 32 + kb + j;
      v[j] = (_Float16)Wout[k * 64 + n];
    }
  }
  *(h8*)&wsW[(size_t)gb * 512 + l * 8] = v;
}

// ------------------------------ main kernel --------------------------------
__global__ void __launch_bounds__(NTHR, 4) lstm_kernel(
    const float* __restrict__ traj, const float* __restrict__ acts,
    const float* __restrict__ bh,   const float* __restrict__ mlpb,
    const float* __restrict__ bout, const _Float16* __restrict__ wsW,
    float* __restrict__ out)
{
  extern __shared__ __align__(16) _Float16 lds[];
  _Float16* As0 = lds;
  _Float16* As1 = lds + LDS_AS;
  _Float16* Wc  = lds + LDS_WCOFF;

  const int tid = threadIdx.x;
  const int w   = tid >> 6;        // wave 0..15: owns h-cols [16w, 16w+16)
  const int l   = tid & 63;
  const int l15 = l & 15;
  const int lq  = l >> 4;
  const int rbase = blockIdx.x * MTILE;

  // Zero both A panels (h starts 0; pad cols 336..359 stay 0 forever).
  for (int i = tid; i < 2 * LDS_AS; i += NTHR) lds[i] = (_Float16)0.f;

  // LDS-resident: 8 blocks/wave = (kt3..4, g0..3), nt = g*16 + w
#pragma unroll
  for (int j = 0; j < WCB; ++j) {
    const int g = j & 3, kt = 3 + (j >> 2);
    const h8 v = *(const h8*)&wsW[(size_t)((g * 16 + w) * NKT + kt) * 512 + l * 8];
    *(h8*)&Wc[(w * WCB + j) * 512 + l * 8] = v;
  }

  // Register-resident: 12 blocks/wave = (kt0..2, g0..3) — AGPR-backed.
  h8 rw[12];
#pragma unroll
  for (int kt = 0; kt < 3; ++kt)
#pragma unroll
    for (int g = 0; g < 4; ++g)
      rw[kt * 4 + g] = *(const h8*)&wsW[(size_t)((g * 16 + w) * NKT + kt) * 512 + l * 8];

  // Persistent cell state + biases (one 16-col group per wave)
  float c[4];
#pragma unroll
  for (int r = 0; r < 4; ++r) c[r] = 0.f;

  float bias[4];
#pragma unroll
  for (int g = 0; g < 4; ++g) bias[g] = bh[g * 256 + w * 16 + l15];

  __syncthreads();

  // Stage x_0 into As0 cols 0..79 (traj via tid<256, acts via tid 256..511)
  if (tid < 256) {
    const int r = tid >> 4, q = tid & 15;
    const float4 v = *(const float4*)&traj[(size_t)(rbase + r) * (TSEQ * DOBS) + q * 4];
    hv4 hx = { (_Float16)v.x, (_Float16)v.y, (_Float16)v.z, (_Float16)v.w };
    *(hv4*)&As0[r * AROW + q * 4] = hx;
  } else if (tid < 512) {
    const int r = (tid - 256) >> 4, q = (tid - 256) & 15;
    As0[r * AROW + 64 + q] = (_Float16)acts[(size_t)(rbase + r) * (TSEQ * DACT) + q];
  }
  __syncthreads();

  unsigned long long wbits = (unsigned long long)(const void*)wsW;

  // Persistent 6-slot stream ring. Primed once here; thereafter each step's
  // last 6 refills prime the next step (stream order periodic mod 24).
  h8 sb[SB_P];
  {
    const _Float16* wlb0 = wsW + (size_t)(w * NKT) * 512 + l * 8;
#pragma unroll
    for (int cc = 0; cc < SB_P; ++cc) sb[cc] = *(const h8*)&wlb0[soff(cc)];
  }

  auto step = [&](int t, const _Float16* buf, _Float16* nbuf) {
    // Memory clobber: stream loads can't be hoisted/CSE'd across steps and
    // rw[] can't be legally rematerialized from wsW.
    asm volatile("" : "+s"(wbits) : : "memory");
    const _Float16* wst = (const _Float16*)wbits;
    const _Float16* wlb = wst + (size_t)(w * NKT) * 512 + l * 8;

    // x(t+1): load to registers now, store to LDS at end of step.
    float4 xv; float xa;
    const bool havex = (t + 1 < TSEQ);
    if (havex) {
      if (tid < 256) {
        const int r = tid >> 4, q = tid & 15;
        xv = *(const float4*)&traj[(size_t)(rbase + r) * (TSEQ * DOBS) + (t + 1) * DOBS + q * 4];
      } else if (tid < 512) {
        const int r = (tid - 256) >> 4, q = (tid - 256) & 15;
        xa = acts[(size_t)(rbase + r) * (TSEQ * DACT) + (t + 1) * DACT + q];
      }
    }

    // ---------------- K-loop: rw (kt0..2) + Wc (kt3..4) + stream (kt5..10) -
    f4 acc[4];
#pragma unroll
    for (int g = 0; g < 4; ++g) acc[g] = f4{0.f, 0.f, 0.f, 0.f};

#pragma unroll
    for (int kt = 0; kt < NKT; ++kt) {
      const h8 a0 = *(const h8*)&buf[l15 * AROW + kt * 32 + lq * 8];
#pragma unroll
      for (int g = 0; g < 4; ++g) {
        if (kt < 3) {
          acc[g] = __builtin_amdgcn_mfma_f32_16x16x32_f16(a0, rw[kt * 4 + g], acc[g], 0, 0, 0);
        } else if (kt < 5) {
          const h8 bf = *(const h8*)&Wc[(w * WCB + (kt - 3) * 4 + g) * 512 + l * 8];
          acc[g] = __builtin_amdgcn_mfma_f32_16x16x32_f16(a0, bf, acc[g], 0, 0, 0);
        } else {
          const int cc = (kt - 5) * 4 + g;
          acc[g] = __builtin_amdgcn_mfma_f32_16x16x32_f16(a0, sb[cc % SB_P], acc[g], 0, 0, 0);
          sb[cc % SB_P] = *(const h8*)&wlb[soff((cc + SB_P) % NSTREAM)];
        }
      }
    }

    // ---------------- cell update (fused-rcp: 5 exp + 3 rcp per r) ---------
    const float KE = -1.44269504088896f;   // -log2(e)
    {
      const int colh = 80 + w * 16 + l15;
#pragma unroll
      for (int r = 0; r < 4; ++r) {
        const float zi = acc[0][r] + bias[0];
        const float zf = acc[1][r] + bias[1];
        const float zg = acc[2][r] + bias[2];
        const float zo = acc[3][r] + bias[3];
        const float ei = __builtin_amdgcn_exp2f(zi * KE);
        const float ef = __builtin_amdgcn_exp2f(zf * KE);
        const float eg = __builtin_amdgcn_exp2f(zg * KE);
        const float eo = __builtin_amdgcn_exp2f(zo * KE);
        const float fg = __builtin_amdgcn_rcpf(1.f + ef);
        const float igg = zg * __builtin_amdgcn_rcpf((1.f + ei) * (1.f + eg)); // i*g
        const float cn = fg * c[r] + igg;
        c[r] = cn;
        const float ec = __builtin_amdgcn_exp2f(cn * KE);
        const float hn = cn * __builtin_amdgcn_rcpf((1.f + eo) * (1.f + ec)); // o*silu(c)
        nbuf[(lq * 4 + r) * AROW + colh] = (_Float16)hn;
      }
    }

    // Deferred x(t+1) store into nbuf cols 0..79.
    if (havex) {
      if (tid < 256) {
        const int r = tid >> 4, q = tid & 15;
        hv4 hx = { (_Float16)xv.x, (_Float16)xv.y, (_Float16)xv.z, (_Float16)xv.w };
        *(hv4*)&nbuf[r * AROW + q * 4] = hx;
      } else if (tid < 512) {
        const int r = (tid - 256) >> 4, q = (tid - 256) & 15;
        nbuf[r * AROW + 64 + q] = (_Float16)xa;
      }
    }
  };

#pragma unroll 1
  for (int t = 0; t < TSEQ; t += 2) {
    step(t, As0, As1);
    lds_barrier();           // LDS-only: stream ring stays in flight
    step(t + 1, As1, As0);
    lds_barrier();
  }

  // ---------------- MLP head ----------------
  // Final h in As0 cols 80..335. Move to As1 cols 0..255.
  for (int i = tid; i < MTILE * HD; i += NTHR) {
    const int r = i >> 8, cc = i & 255;
    As1[r * AROW + cc] = As0[r * AROW + 80 + cc];
  }
  __syncthreads();

#pragma unroll 1
  for (int L = 0; L < NL; ++L) {
    const _Float16* in = (L & 1) ? As0 : As1;
    _Float16*       ob = (L & 1) ? As1 : As0;
    const _Float16* wl = wsW + WS_MLP + (size_t)L * (128 * 512);
    const float bcol = mlpb[L * HD + w * 16 + l15];

    f4 acc = f4{0.f, 0.f, 0.f, 0.f};
#pragma unroll
    for (int kt = 0; kt < 8; ++kt) {
      const h8 a0 = *(const h8*)&in[l15 * AROW + kt * 32 + lq * 8];
      const h8 bf = *(const h8*)&wl[(size_t)(w * 8 + kt) * 512 + l * 8];
      acc = __builtin_amdgcn_mfma_f32_16x16x32_f16(a0, bf, acc, 0, 0, 0);
    }
#pragma unroll
    for (int r = 0; r < 4; ++r) {
      const float z = acc[r] + bcol;
      const float ez = __builtin_amdgcn_exp2f(z * -1.44269504088896f);
      ob[(lq * 4 + r) * AROW + w * 16 + l15] =
          (_Float16)(z * __builtin_amdgcn_rcpf(1.f + ez));
    }
    __syncthreads();
  }

  // Output layer: final activations in As0 (NL=5 odd). N=64 -> waves 0..3.
  if (w < 4) {
    const _Float16* wo = wsW + WS_WOUT;
    const float bo = bout[w * 16 + l15];
    f4 acc = f4{0.f, 0.f, 0.f, 0.f};
#pragma unroll
    for (int kt = 0; kt < 8; ++kt) {
      const h8 a0 = *(const h8*)&As0[l15 * AROW + kt * 32 + lq * 8];
      const h8 bf = *(const h8*)&wo[(size_t)(w * 8 + kt) * 512 + l * 8];
      acc = __builtin_amdgcn_mfma_f32_16x16x32_f16(a0, bf, acc, 0, 0, 0);
    }
#pragma unroll
    for (int r = 0; r < 4; ++r)
      out[(size_t)(rbase + lq * 4 + r) * DOUT + w * 16 + l15] = acc[r] + bo;
  }
}

// ------------------------------- launcher ----------------------------------
extern "C" void kernel_launch(void* const* d_in, const int* in_sizes, int n_in,
                              void* d_out, int out_size, void* d_ws, size_t ws_size,
                              hipStream_t stream)
{
  const float* traj = (const float*)d_in[0];
  const float* acts = (const float*)d_in[1];
  const float* Wi   = (const float*)d_in[2];
  const float* Wh   = (const float*)d_in[3];
  const float* bh   = (const float*)d_in[4];
  const float* mlpW = (const float*)d_in[5];
  const float* mlpb = (const float*)d_in[6];
  const float* Wout = (const float*)d_in[7];
  const float* bout = (const float*)d_in[8];
  _Float16* wsW = (_Float16*)d_ws;   // needs 1,409,024 bytes of workspace

  (void)hipFuncSetAttribute((const void*)lstm_kernel,
                            hipFuncAttributeMaxDynamicSharedMemorySize, LDS_BYTES);

  repack_kernel<<<344, 256, 0, stream>>>(Wi, Wh, mlpW, Wout, wsW);
  lstm_kernel<<<NWG, NTHR, LDS_BYTES, stream>>>(traj, acts, bh, mlpb, bout, wsW, (float*)d_out);
}